// Round 18
// baseline (407.009 us; speedup 1.0000x reference)
//
#include <hip/hip_runtime.h>
#include <math.h>

// ---------------- constants from the reference ----------------
#define T_ 3
#define R_ 4
#define L_ 2
#define H_ 256
#define HEADS_ 8
#define D_ 32
#define FIN_ 128
#define OUT_ 128

typedef unsigned short bf16_t;
typedef __attribute__((ext_vector_type(8))) short bf16x8;
typedef __attribute__((ext_vector_type(4))) float f32x4;

__device__ __forceinline__ float bf2f(bf16_t h) {
    return __uint_as_float(((unsigned)h) << 16);
}
__device__ __forceinline__ float bflo(unsigned u) {
    return __uint_as_float(u << 16);
}
__device__ __forceinline__ float bfhi(unsigned u) {
    return __uint_as_float(u & 0xffff0000u);
}
__device__ __forceinline__ bf16_t f2bf(float f) {
    unsigned u = __float_as_uint(f);
    u += 0x7FFFu + ((u >> 16) & 1u);
    return (bf16_t)(u >> 16);
}
__device__ __forceinline__ float gelu_exact(float x) {
    return 0.5f * x * (1.0f + erff(x * 0.70710678118654752440f));
}
// packed bf16x2 dot: d = a.lo*b.lo + a.hi*b.hi + c   (VOP3P, CDNA2+)
__device__ __forceinline__ float dot2bf(unsigned a, unsigned b, float c) {
    float d;
    asm("v_dot2_f32_bf16 %0, %1, %2, %3" : "=v"(d) : "v"(a), "v"(b), "v"(c));
    return d;
}

// ---------------- zero fill ----------------
__global__ void zero_kernel(unsigned* __restrict__ p, long n) {
    long i = (long)blockIdx.x * blockDim.x + threadIdx.x;
    long stride = (long)gridDim.x * blockDim.x;
    for (; i < n; i += stride) p[i] = 0u;
}

// ---------------- all weight preprocessing in ONE kernel ----------------
// z 0..15: fused relation weights (+bias), K/V-interleaved (y=0..7, x=0..3)
// z 16..21: Wq transpose slices; 22..27: Wa; 28..30: Win; 31: Wout (y<4 only)
__global__ __launch_bounds__(256) void prep_all_kernel(
    const float* __restrict__ Wk, const float* __restrict__ Wv,
    const float* __restrict__ bk, const float* __restrict__ bv,
    const float* __restrict__ a_rel, const float* __restrict__ m_rel,
    bf16_t* __restrict__ WkvT, float* __restrict__ bkv,
    const float* __restrict__ Wq, const float* __restrict__ Wa,
    const float* __restrict__ Win, const float* __restrict__ Wout,
    bf16_t* __restrict__ WqT, bf16_t* __restrict__ WaT,
    bf16_t* __restrict__ WinT, bf16_t* __restrict__ WoutT)
{
    const int tid = threadIdx.x;
    if (blockIdx.z < 16) {
        // ---- fuse path ----
        const int s = blockIdx.z;
        const int kv = s & 1, r = (s >> 1) & 3, l = s >> 3;
        const int SRCT[4] = {0, 1, 1, 1};
        const int st = SRCT[r];
        const float* W = (kv ? Wv : Wk) + ((long)l * T_ + st) * H_ * H_;
        const float* A = (kv ? m_rel : a_rel) + ((long)l * R_ + r) * HEADS_ * D_ * D_;
        const int hh = blockIdx.y, kt = blockIdx.x;
        __shared__ float As[32][33];
        __shared__ float Ws[64][33];
        {
            int d = tid >> 3, e4 = (tid & 7) * 4;
            float4 v = *(const float4*)(A + (hh * D_ + d) * D_ + e4);
            As[d][e4] = v.x; As[d][e4 + 1] = v.y; As[d][e4 + 2] = v.z; As[d][e4 + 3] = v.w;
        }
        #pragma unroll
        for (int p = 0; p < 2; ++p) {
            int idx = p * 256 + tid;
            int row = idx >> 3, c4 = (idx & 7) * 4;
            float4 v = *(const float4*)(W + (long)(kt * 64 + row) * H_ + hh * 32 + c4);
            Ws[row][c4] = v.x; Ws[row][c4 + 1] = v.y; Ws[row][c4 + 2] = v.z; Ws[row][c4 + 3] = v.w;
        }
        __syncthreads();
        const int kl = tid & 63, eb = tid >> 6;
        #pragma unroll
        for (int ii = 0; ii < 8; ++ii) {
            int e = eb * 8 + ii;
            float acc = 0.f;
            #pragma unroll
            for (int d = 0; d < 32; ++d)
                acc += As[d][e] * Ws[kl][d];
            int col = hh * 32 + e;
            int pos = (col >> 2) * 8 + kv * 4 + (col & 3);
            long rowIdx = (long)(s >> 1) * 512 + pos;
            WkvT[rowIdx * H_ + kt * 64 + kl] = f2bf(acc);
        }
        if (blockIdx.x == 0 && blockIdx.y == 0) {
            const float* b = (kv ? bv : bk) + ((long)l * T_ + st) * H_;
            const int bh = tid >> 5, be = tid & 31;
            float acc = 0.f;
            #pragma unroll
            for (int d = 0; d < D_; ++d)
                acc += b[bh * D_ + d] * A[(bh * D_ + d) * D_ + be];
            int pos = (tid >> 2) * 8 + kv * 4 + (tid & 3);
            bkv[(long)(s >> 1) * 512 + pos] = acc;
        }
    } else {
        // ---- transpose path ----
        __shared__ float Ls[64][65];
        int z = blockIdx.z - 16;
        const float* in; bf16_t* out; int Rr, Cc;
        if (z < 6)       { in = Wq;   out = WqT;   Rr = 256; Cc = 256; }
        else if (z < 12) { in = Wa;   out = WaT;   Rr = 256; Cc = 256; z -= 6; }
        else if (z < 15) { in = Win;  out = WinT;  Rr = 128; Cc = 256; z -= 12; }
        else             { in = Wout; out = WoutT; Rr = 256; Cc = 128; z = 0; }
        const int r0 = blockIdx.y * 64, c0 = blockIdx.x * 64;
        if (r0 >= Rr || c0 >= Cc || blockIdx.x >= 4) return;
        const long base = (long)z * Rr * Cc;
        #pragma unroll
        for (int i = 0; i < 16; ++i) {
            int e = tid + i * 256; int row = e >> 6, col = e & 63;
            Ls[row][col] = in[base + (long)(r0 + row) * Cc + c0 + col];
        }
        __syncthreads();
        #pragma unroll
        for (int i = 0; i < 16; ++i) {
            int e = tid + i * 256; int row = e >> 6, col = e & 63;
            out[base + (long)(c0 + row) * Rr + r0 + col] = f2bf(Ls[col][row]);
        }
    }
}

// ---------------- CSR build (parallel scan, 6 small launches) ----------------
__global__ void hist_kernel(const int* __restrict__ ei, int* __restrict__ indeg,
                            int Nn, int E)
{
    int idx = blockIdx.x * 256 + threadIdx.x;
    if (idx >= R_ * E) return;
    int r = idx / E, e = idx - r * E;
    int d = ei[(size_t)r * 2 * E + E + e];
    atomicAdd(indeg + (size_t)r * Nn + d, 1);
}

__global__ __launch_bounds__(256) void csr_part_kernel(
    const int* __restrict__ indeg, int* __restrict__ partials, int Nn, int nch)
{
    const int r = blockIdx.y, c = blockIdx.x, tid = threadIdx.x;
    const int lane = tid & 63, wave = tid >> 6;
    int idx = c * 256 + tid;
    int v = (idx < Nn) ? indeg[(size_t)r * Nn + idx] : 0;
    #pragma unroll
    for (int off = 1; off < 64; off <<= 1) v += __shfl_xor(v, off);
    __shared__ int wsum[4];
    if (lane == 0) wsum[wave] = v;
    __syncthreads();
    if (tid == 0) partials[r * nch + c] = wsum[0] + wsum[1] + wsum[2] + wsum[3];
}

__global__ __launch_bounds__(256) void csr_scanpart_kernel(
    int* __restrict__ partials, int nch)
{
    const int r = blockIdx.x, tid = threadIdx.x;
    __shared__ int sh[256];
    int v = (tid < nch) ? partials[r * nch + tid] : 0;
    sh[tid] = v;
    __syncthreads();
    for (int off = 1; off < 256; off <<= 1) {
        int u = (tid >= off) ? sh[tid - off] : 0;
        __syncthreads();
        sh[tid] += u;
        __syncthreads();
    }
    if (tid < nch) partials[r * nch + tid] = sh[tid] - v;   // exclusive
}

__global__ __launch_bounds__(256) void csr_write_kernel(
    const int* __restrict__ indeg, const int* __restrict__ partials,
    int* __restrict__ offs, int* __restrict__ cursor, int Nn, int nch)
{
    const int r = blockIdx.y, c = blockIdx.x, tid = threadIdx.x;
    int idx = c * 256 + tid;
    int v = (idx < Nn) ? indeg[(size_t)r * Nn + idx] : 0;
    __shared__ int sh[256];
    sh[tid] = v;
    __syncthreads();
    for (int off = 1; off < 256; off <<= 1) {
        int u = (tid >= off) ? sh[tid - off] : 0;
        __syncthreads();
        sh[tid] += u;
        __syncthreads();
    }
    int incl = sh[tid];
    int base = partials[r * nch + c];
    if (idx < Nn) {
        int excl = base + incl - v;
        offs[(size_t)r * (Nn + 1) + idx] = excl;
        cursor[(size_t)r * Nn + idx] = excl;
        if (idx == Nn - 1) offs[(size_t)r * (Nn + 1) + Nn] = base + incl;
    }
}

// esrc stores PRE-SCALED element offsets (src * 512)
__global__ void scatter_kernel(const int* __restrict__ ei, int* __restrict__ cursor,
                               int* __restrict__ esrc, int Nn, int E)
{
    int idx = blockIdx.x * 256 + threadIdx.x;
    if (idx >= R_ * E) return;
    int r = idx / E, e = idx - r * E;
    int s = ei[(size_t)r * 2 * E + e];
    int d = ei[(size_t)r * 2 * E + E + e];
    int pos = atomicAdd(cursor + (size_t)r * Nn + d, 1);
    esrc[(size_t)r * E + pos] = s * 512;
}

// ---------------- batched per-node attention aggregation ----------------
// 512-thread blocks (8 nodes/block) to halve block-dispatch churn.
// Dual-chain batch-2, scalar state (rule #20), branchless validity,
// K/V interleaved rows, deferred-max exp2 domain, v_dot2_f32_bf16 QK dot.
// Per-relation INDEPENDENT softmax; normalized results summed (matches ref).
#define STEP(rr, vld, prX, mX, sX, x0, x1, x2, x3)                          \
    {                                                                        \
        float dt_ = dot2bf(rr.y, quy, dot2bf(rr.x, qux, 0.f));               \
        dt_ += __shfl_xor(dt_, 1);                                           \
        dt_ += __shfl_xor(dt_, 2);                                           \
        dt_ += __shfl_xor(dt_, 4);                                           \
        float lg = (vld) ? dt_ * prX : -1e30f;                               \
        if (__any(lg - mX > 11.5415603f)) {                                  \
            float mn = fmaxf(mX, lg);                                        \
            float fac = exp2f(mX - mn);                                      \
            float p = exp2f(lg - mn);                                        \
            p = (vld) ? p : 0.f;                                             \
            sX = sX * fac + p;                                               \
            x0 = x0 * fac + p * bflo(rr.z);                                  \
            x1 = x1 * fac + p * bfhi(rr.z);                                  \
            x2 = x2 * fac + p * bflo(rr.w);                                  \
            x3 = x3 * fac + p * bfhi(rr.w);                                  \
            mX = mn;                                                         \
        } else {                                                             \
            float p = exp2f(lg - mX);                                        \
            p = (vld) ? p : 0.f;                                             \
            sX += p;                                                         \
            x0 += p * bflo(rr.z);                                            \
            x1 += p * bfhi(rr.z);                                            \
            x2 += p * bflo(rr.w);                                            \
            x3 += p * bfhi(rr.w);                                            \
        }                                                                    \
    }

__global__ __launch_bounds__(512) void agg_all_kernel(
    const int* __restrict__ offs, const int* __restrict__ esrc,
    bf16_t* __restrict__ qbuf, const bf16_t* __restrict__ KV,
    const float* __restrict__ p_l, float scale2, int Nn, int E)
{
    static const int NRELg[3] = {2, 1, 1};
    static const int R0g[3]  = {0, 1, 3};
    static const int R1g[3]  = {2, 0, 0};
    static const int DTg[3]  = {1, 0, 2};
    const int grp = blockIdx.y;
    const int wave = threadIdx.x >> 6, lane = threadIdx.x & 63;
    const int d = blockIdx.x * 8 + wave;
    if (d >= Nn) return;
    const int head = lane >> 3;
    const int dt = DTg[grp];
    const bool separate = (NRELg[grp] == 2);

    bf16_t* qrow = qbuf + ((size_t)dt * Nn + d) * H_;
    uint2 qu = ((const uint2*)qrow)[lane];
    const unsigned qux = qu.x, quy = qu.y;

    const int rA = R0g[grp];
    const int* esA = esrc + (size_t)rA * E;
    const bf16_t* kvA = KV + (size_t)rA * Nn * 512;
    float prA = p_l[rA * HEADS_ + head] * scale2;
    int curA = offs[(size_t)rA * (Nn + 1) + d];
    int endA = offs[(size_t)rA * (Nn + 1) + d + 1];

    const int* esB; const bf16_t* kvB; float prB;
    int curB, endB;
    if (separate) {
        const int rB = R1g[grp];
        esB = esrc + (size_t)rB * E;
        kvB = KV + (size_t)rB * Nn * 512;
        prB = p_l[rB * HEADS_ + head] * scale2;
        curB = offs[(size_t)rB * (Nn + 1) + d];
        endB = offs[(size_t)rB * (Nn + 1) + d + 1];
    } else {
        int mid = curA + ((endA - curA + 1) >> 1);
        esB = esA; kvB = kvA; prB = prA;
        curB = mid; endB = endA;
        endA = mid;
    }
    const int safeA = (endA > 0) ? endA - 1 : 0;
    const int safeB = (endB > 0) ? endB - 1 : 0;
    const int loff = lane * 8;

    float mA = -INFINITY, sA = 0.f, aA0 = 0.f, aA1 = 0.f, aA2 = 0.f, aA3 = 0.f;
    float mB = -INFINITY, sB = 0.f, aB0 = 0.f, aB1 = 0.f, aB2 = 0.f, aB3 = 0.f;

    while (curA < endA || curB < endB) {
        bool vA0 = curA < endA, vA1 = curA + 1 < endA;
        bool vB0 = curB < endB, vB1 = curB + 1 < endB;
        uint4 rA0, rA1, rB0, rB1;
        if (vA0) {
            int i0 = esA[curA];
            int i1 = esA[min(curA + 1, safeA)];
            rA0 = *(const uint4*)(kvA + i0 + loff);
            rA1 = *(const uint4*)(kvA + i1 + loff);
        }
        if (vB0) {
            int i0 = esB[curB];
            int i1 = esB[min(curB + 1, safeB)];
            rB0 = *(const uint4*)(kvB + i0 + loff);
            rB1 = *(const uint4*)(kvB + i1 + loff);
        }
        if (vA0) {
            STEP(rA0, true, prA, mA, sA, aA0, aA1, aA2, aA3)
            STEP(rA1, vA1, prA, mA, sA, aA0, aA1, aA2, aA3)
            curA += 2;
        }
        if (vB0) {
            STEP(rB0, true, prB, mB, sB, aB0, aB1, aB2, aB3)
            STEP(rB1, vB1, prB, mB, sB, aB0, aB1, aB2, aB3)
            curB += 2;
        }
    }

    float t0, t1, t2, t3;
    if (separate) {
        float iA = (sA > 0.f) ? 1.f / sA : 0.f;
        float iB = (sB > 0.f) ? 1.f / sB : 0.f;
        t0 = aA0 * iA + aB0 * iB;
        t1 = aA1 * iA + aB1 * iB;
        t2 = aA2 * iA + aB2 * iB;
        t3 = aA3 * iA + aB3 * iB;
    } else {
        if (sB > 0.f) {   // exact merge of the two half-range chains
            float mm = fmaxf(mA, mB);
            float fx = (sA > 0.f) ? exp2f(mA - mm) : 0.f;
            float fy = exp2f(mB - mm);
            sA = sA * fx + sB * fy;
            aA0 = aA0 * fx + aB0 * fy;
            aA1 = aA1 * fx + aB1 * fy;
            aA2 = aA2 * fx + aB2 * fy;
            aA3 = aA3 * fx + aB3 * fy;
        }
        float iA = (sA > 0.f) ? 1.f / sA : 0.f;
        t0 = aA0 * iA; t1 = aA1 * iA; t2 = aA2 * iA; t3 = aA3 * iA;
    }
    ushort4 ou;
    ou.x = f2bf(gelu_exact(t0));
    ou.y = f2bf(gelu_exact(t1));
    ou.z = f2bf(gelu_exact(t2));
    ou.w = f2bf(gelu_exact(t3));
    ((ushort4*)qrow)[lane] = ou;
}

// ---------------- MFMA bf16 GEMM ----------------
// Epilogue staging buffer ALIASES As (dead after the K loop).
#define ASTR 40
#define ESTR 72

template<typename TA, typename TC, int ACT_C>
__global__ __launch_bounds__(256) void mfma_gemm(
    const TA* __restrict__ A, const TA* __restrict__ A2, int zsplit,
    const bf16_t* __restrict__ BT,
    const float* __restrict__ bias, TC* __restrict__ C,
    int M, int K, int Nc,
    long strideA, long strideB, long strideBias, long strideC)
{
    const int gX = gridDim.x, gY = gridDim.y, gZ = gridDim.z;
    const int nwg = gX * gY * gZ;
    int flat = blockIdx.x + gX * (blockIdx.y + gY * blockIdx.z);
    const int qch = nwg >> 3, rch = nwg & 7;
    int xcd = flat & 7, cidx = flat >> 3;
    int swz = (xcd < rch ? xcd * (qch + 1) : rch * (qch + 1) + (xcd - rch) * qch) + cidx;
    const int by = swz / (gX * gZ);
    int rem = swz - by * (gX * gZ);
    const int bz = rem / gX;
    const int bx = rem - bz * gX;

    const TA* Ab = (bz < zsplit) ? (A + (long)bz * strideA) : A2;
    const bf16_t* Bb = BT + (long)bz * strideB;
    const float* biasb = bias + (long)bz * strideBias;
    TC* Cb = C + (long)bz * strideC;

    __shared__ bf16_t As[128 * ASTR];
    __shared__ bf16_t Bs[128 * ASTR];
    const int tid = threadIdx.x;
    const int lane = tid & 63, wave = tid >> 6;
    const int wr = wave >> 1, wc = wave & 1;
    const int bm = by * 128, bn = bx * 128;
    const int r16 = lane & 15, g = lane >> 4;
    f32x4 acc[4][4] = {};

    for (int k0 = 0; k0 < K; k0 += 32) {
        #pragma unroll
        for (int p = 0; p < 2; ++p) {
            int idx = p * 256 + tid;
            int row = idx >> 2, seg = idx & 3;
            int grow = bm + row;
            bf16x8 av = {};
            if (grow < M) {
                if constexpr (sizeof(TA) == 2) {
                    av = *(const bf16x8*)(Ab + (long)grow * K + k0 + seg * 8);
                } else {
                    const float* sp = (const float*)Ab + (long)grow * K + k0 + seg * 8;
                    float4 f0 = *(const float4*)sp, f1 = *(const float4*)(sp + 4);
                    av[0] = (short)f2bf(f0.x); av[1] = (short)f2bf(f0.y);
                    av[2] = (short)f2bf(f0.z); av[3] = (short)f2bf(f0.w);
                    av[4] = (short)f2bf(f1.x); av[5] = (short)f2bf(f1.y);
                    av[6] = (short)f2bf(f1.z); av[7] = (short)f2bf(f1.w);
                }
            }
            *(bf16x8*)(As + row * ASTR + seg * 8) = av;
            bf16x8 bv = *(const bf16x8*)(Bb + (long)(bn + row) * K + k0 + seg * 8);
            *(bf16x8*)(Bs + row * ASTR + seg * 8) = bv;
        }
        __syncthreads();
        bf16x8 af[4], bfr[4];
        #pragma unroll
        for (int m = 0; m < 4; ++m)
            af[m] = *(const bf16x8*)(As + (wr * 64 + m * 16 + r16) * ASTR + g * 8);
        #pragma unroll
        for (int n = 0; n < 4; ++n)
            bfr[n] = *(const bf16x8*)(Bs + (wc * 64 + n * 16 + r16) * ASTR + g * 8);
        #pragma unroll
        for (int m = 0; m < 4; ++m)
            #pragma unroll
            for (int n = 0; n < 4; ++n)
                acc[m][n] = __builtin_amdgcn_mfma_f32_16x16x32_bf16(af[m], bfr[n], acc[m][n], 0, 0, 0);
        __syncthreads();
    }

    float bb[4];
    #pragma unroll
    for (int n = 0; n < 4; ++n)
        bb[n] = biasb[bn + wc * 64 + n * 16 + r16];

    if constexpr (sizeof(TC) == 2) {
        bf16_t* st = As + wave * (16 * ESTR);   // Es aliases As (dead)
        #pragma unroll
        for (int m = 0; m < 4; ++m) {
            int rowbase = bm + wr * 64 + m * 16;
            #pragma unroll
            for (int n = 0; n < 4; ++n) {
                #pragma unroll
                for (int j = 0; j < 4; ++j) {
                    float vv = acc[m][n][j] + bb[n];
                    if (ACT_C) vv = fmaxf(vv, 0.f);
                    st[(g * 4 + j) * ESTR + n * 16 + r16] = f2bf(vv);
                }
            }
            #pragma unroll
            for (int p = 0; p < 2; ++p) {
                int row = p * 8 + (lane >> 3);
                int col0 = (lane & 7) * 8;
                int grow = rowbase + row;
                bf16x8 val = *(const bf16x8*)(st + row * ESTR + col0);
                if (grow < M)
                    *(bf16x8*)(Cb + (long)grow * Nc + bn + wc * 64 + col0) = val;
            }
        }
    } else {
        #pragma unroll
        for (int n = 0; n < 4; ++n) {
            int col = bn + wc * 64 + n * 16 + r16;
            #pragma unroll
            for (int m = 0; m < 4; ++m) {
                int rowbase = bm + wr * 64 + m * 16 + g * 4;
                #pragma unroll
                for (int j = 0; j < 4; ++j) {
                    int row = rowbase + j;
                    if (row < M) {
                        float vv = acc[m][n][j] + bb[n];
                        if (ACT_C) vv = fmaxf(vv, 0.f);
                        Cb[(long)row * Nc + col] = vv;
                    }
                }
            }
        }
    }
}

// ---------------- fused Wa-GEMM + skip-gate + residual + LN + ReLU ----------
// Epilogue/residual staging ALIASES Bs (dead after K loop).
__global__ __launch_bounds__(512) void gemm_ln_kernel(
    const bf16_t* __restrict__ A, const bf16_t* __restrict__ BT,
    const float* __restrict__ bias, bf16_t* __restrict__ h,
    const float* __restrict__ skip_l, const float* __restrict__ ln_g,
    const float* __restrict__ ln_b, int M)
{
    const int gY = gridDim.y;
    const int nwg = gY * 3;
    int flat = blockIdx.y + gY * blockIdx.z;
    const int qch = nwg >> 3, rch = nwg & 7;
    int xcd = flat & 7, cidx = flat >> 3;
    int swz = (xcd < rch ? xcd * (qch + 1) : rch * (qch + 1) + (xcd - rch) * qch) + cidx;
    const int by = swz / 3;
    const int bz = swz - by * 3;

    const bf16_t* Ab = A + (long)bz * M * H_;
    const bf16_t* Bb = BT + (long)bz * H_ * H_;
    const float* biasb = bias + bz * H_;
    bf16_t* hb = h + (long)bz * M * H_;
    const float* lgp = ln_g + bz * H_;
    const float* lbp = ln_b + bz * H_;

    __shared__ bf16_t As[128 * ASTR];
    __shared__ bf16_t Bs[256 * ASTR];
    __shared__ float  sums[128][4][2];

    const int tid = threadIdx.x;
    const int lane = tid & 63, wave = tid >> 6;
    const int wr = wave >> 2, wc = wave & 3;
    const int bm = by * 128;
    const int r16 = lane & 15, g = lane >> 4;
    f32x4 acc[4][4] = {};

    for (int k0 = 0; k0 < H_; k0 += 32) {
        {
            int row = tid >> 2, seg = tid & 3;
            int grow = bm + row;
            bf16x8 av = {};
            if (grow < M) av = *(const bf16x8*)(Ab + (long)grow * H_ + k0 + seg * 8);
            *(bf16x8*)(As + row * ASTR + seg * 8) = av;
        }
        #pragma unroll
        for (int p = 0; p < 2; ++p) {
            int idx = p * 512 + tid;
            int row = idx >> 2, seg = idx & 3;
            bf16x8 bv = *(const bf16x8*)(Bb + (long)row * H_ + k0 + seg * 8);
            *(bf16x8*)(Bs + row * ASTR + seg * 8) = bv;
        }
        __syncthreads();
        bf16x8 af[4], bfr[4];
        #pragma unroll
        for (int m = 0; m < 4; ++m)
            af[m] = *(const bf16x8*)(As + (wr * 64 + m * 16 + r16) * ASTR + g * 8);
        #pragma unroll
        for (int n = 0; n < 4; ++n)
            bfr[n] = *(const bf16x8*)(Bs + (wc * 64 + n * 16 + r16) * ASTR + g * 8);
        #pragma unroll
        for (int m = 0; m < 4; ++m)
            #pragma unroll
            for (int n = 0; n < 4; ++n)
                acc[m][n] = __builtin_amdgcn_mfma_f32_16x16x32_bf16(af[m], bfr[n], acc[m][n], 0, 0, 0);
        __syncthreads();
    }

    const float beta = 1.f / (1.f + __expf(-skip_l[bz]));
    const float cb = 2.f - beta;
    const int colb = wc * 64;
    float bb[4], lng[4], lnb[4];
    #pragma unroll
    for (int n = 0; n < 4; ++n) {
        int col = colb + n * 16 + r16;
        bb[n] = biasb[col]; lng[n] = lgp[col]; lnb[n] = lbp[col];
    }

    bf16_t* st = Bs + wave * (16 * ESTR);
    #pragma unroll
    for (int m = 0; m < 4; ++m) {
        #pragma unroll
        for (int p = 0; p < 2; ++p) {
            int row = p * 8 + (lane >> 3);
            int col0 = (lane & 7) * 8;
            int grow = bm + wr * 64 + m * 16 + row;
            bf16x8 hv = {};
            if (grow < M) hv = *(const bf16x8*)(hb + (long)grow * H_ + colb + col0);
            *(bf16x8*)(st + row * ESTR + col0) = hv;
        }
        #pragma unroll
        for (int j = 0; j < 4; ++j) {
            int lrow = wr * 64 + m * 16 + g * 4 + j;
            float s1 = 0.f, s2 = 0.f;
            #pragma unroll
            for (int n = 0; n < 4; ++n) {
                float o = acc[m][n][j] + bb[n];
                float hv = bf2f(st[(g * 4 + j) * ESTR + n * 16 + r16]);
                float u = beta * o + cb * hv;
                acc[m][n][j] = u;
                s1 += u; s2 += u * u;
            }
            s1 += __shfl_xor(s1, 1); s2 += __shfl_xor(s2, 1);
            s1 += __shfl_xor(s1, 2); s2 += __shfl_xor(s2, 2);
            s1 += __shfl_xor(s1, 4); s2 += __shfl_xor(s2, 4);
            s1 += __shfl_xor(s1, 8); s2 += __shfl_xor(s2, 8);
            if (r16 == 0) { sums[lrow][wc][0] = s1; sums[lrow][wc][1] = s2; }
        }
    }
    __syncthreads();

    #pragma unroll
    for (int m = 0; m < 4; ++m) {
        #pragma unroll
        for (int j = 0; j < 4; ++j) {
            int lrow = wr * 64 + m * 16 + g * 4 + j;
            float S1 = sums[lrow][0][0] + sums[lrow][1][0] + sums[lrow][2][0] + sums[lrow][3][0];
            float S2 = sums[lrow][0][1] + sums[lrow][1][1] + sums[lrow][2][1] + sums[lrow][3][1];
            float mu = S1 * (1.f / H_);
            float var = S2 * (1.f / H_) - mu * mu;
            float inv = rsqrtf(var + 1e-5f);
            #pragma unroll
            for (int n = 0; n < 4; ++n) {
                float r = fmaxf((acc[m][n][j] - mu) * inv * lng[n] + lnb[n], 0.f);
                st[(g * 4 + j) * ESTR + n * 16 + r16] = f2bf(r);
            }
        }
        #pragma unroll
        for (int p = 0; p < 2; ++p) {
            int row = p * 8 + (lane >> 3);
            int col0 = (lane & 7) * 8;
            int grow = bm + wr * 64 + m * 16 + row;
            bf16x8 val = *(const bf16x8*)(st + row * ESTR + col0);
            if (grow < M)
                *(bf16x8*)(hb + (long)grow * H_ + colb + col0) = val;
        }
    }
}

// ---------------- host side ----------------
extern "C" void kernel_launch(void* const* d_in, const int* in_sizes, int n_in,
                              void* d_out, int out_size, void* d_ws, size_t ws_size,
                              hipStream_t stream)
{
    const float* x     = (const float*)d_in[0];
    const int*   ei    = (const int*)  d_in[1];
    const float* Win   = (const float*)d_in[2];
    const float* b_in  = (const float*)d_in[3];
    const float* Wk    = (const float*)d_in[4];
    const float* bk    = (const float*)d_in[5];
    const float* Wq    = (const float*)d_in[6];
    const float* bq    = (const float*)d_in[7];
    const float* Wv    = (const float*)d_in[8];
    const float* bv    = (const float*)d_in[9];
    const float* Wa    = (const float*)d_in[10];
    const float* ba    = (const float*)d_in[11];
    const float* skip  = (const float*)d_in[12];
    const float* a_rel = (const float*)d_in[13];
    const float* m_rel = (const float*)d_in[14];
    const float* p_rel = (const float*)d_in[15];
    const float* ln_g  = (const float*)d_in[16];
    const float* ln_b  = (const float*)d_in[17];
    const float* Wout  = (const float*)d_in[18];
    const float* bout  = (const float*)d_in[19];
    float* out = (float*)d_out;

    const int N = in_sizes[0] / (T_ * FIN_);
    const int E = in_sizes[1] / (R_ * 2);
    const size_t NH = (size_t)N * H_;
    const int nch = (N + 255) / 256;
    const int ZBIG = 1 << 20;

    char* wp = (char*)d_ws;
    auto alloc = [&](size_t bytes) {
        void* r = wp;
        wp += (bytes + 255) & ~(size_t)255;
        return r;
    };
    bf16_t* h     = (bf16_t*)alloc(T_ * NH * 2);
    bf16_t* qbuf  = (bf16_t*)alloc(T_ * NH * 2);
    bf16_t* KV    = (bf16_t*)alloc((size_t)R_ * N * 512 * 2);
    int*    indeg = (int*)   alloc((size_t)R_ * N * 4);
    int*    offs  = (int*)   alloc((size_t)R_ * (N + 1) * 4);
    int*    cursor= (int*)   alloc((size_t)R_ * N * 4);
    int*    esrc  = (int*)   alloc((size_t)R_ * E * 4);
    int*    parts = (int*)   alloc((size_t)R_ * 256 * 4);
    bf16_t* WqT   = (bf16_t*)alloc((size_t)L_ * T_ * H_ * H_ * 2);
    bf16_t* WaT   = (bf16_t*)alloc((size_t)L_ * T_ * H_ * H_ * 2);
    bf16_t* WinT  = (bf16_t*)alloc((size_t)T_ * FIN_ * H_ * 2);
    bf16_t* WoutT = (bf16_t*)alloc((size_t)H_ * OUT_ * 2);
    bf16_t* WkvT  = (bf16_t*)alloc((size_t)L_ * R_ * 512 * H_ * 2);
    float*  bkv   = (float*) alloc((size_t)L_ * R_ * 512 * 4);

    if ((size_t)(wp - (char*)d_ws) > ws_size) return;   // clean-fail guard

    const float scale2 = 0.17677669529663688f * 1.4426950408889634f;  // /sqrt(32)*log2e
    dim3 blk(256);
    auto gM = [](long M) { return (int)((M + 127) / 128); };

    // ---- weight preprocessing (1 launch) ----
    prep_all_kernel<<<dim3(4, 8, 32), blk, 0, stream>>>(
        Wk, Wv, bk, bv, a_rel, m_rel, WkvT, bkv,
        Wq, Wa, Win, Wout, WqT, WaT, WinT, WoutT);

    // ---- CSR build (parallel, 6 small launches) ----
    zero_kernel<<<256, blk, 0, stream>>>((unsigned*)indeg, (long)R_ * N);
    hist_kernel<<<(R_ * E + 255) / 256, blk, 0, stream>>>(ei, indeg, N, E);
    csr_part_kernel<<<dim3(nch, R_), blk, 0, stream>>>(indeg, parts, N, nch);
    csr_scanpart_kernel<<<R_, blk, 0, stream>>>(parts, nch);
    csr_write_kernel<<<dim3(nch, R_), blk, 0, stream>>>(indeg, parts, offs, cursor, N, nch);
    scatter_kernel<<<(R_ * E + 255) / 256, blk, 0, stream>>>(ei, cursor, esrc, N, E);

    // ---- input projection + relu ----
    mfma_gemm<float, bf16_t, 1><<<dim3(H_ / 128, gM(N), T_), blk, 0, stream>>>(
        x, x, ZBIG, WinT, b_in, h, N, FIN_, H_,
        (long)N * FIN_, (long)FIN_ * H_, H_, (long)NH);

    for (int l = 0; l < L_; ++l) {
        const long lw = (long)l * R_;
        // KV for all 4 relations (interleaved k|v columns): z=4
        mfma_gemm<bf16_t, bf16_t, 0><<<dim3(512 / 128, gM(N), 4), blk, 0, stream>>>(
            h, h + NH, 1, WkvT + lw * 512 * H_, bkv + lw * 512, KV,
            N, H_, 512, 0L, 512L * H_, 512L, (long)N * 512);
        // q for all 3 node types: z=3
        mfma_gemm<bf16_t, bf16_t, 0><<<dim3(H_ / 128, gM(N), 3), blk, 0, stream>>>(
            h, h, ZBIG, WqT + (size_t)l * T_ * H_ * H_, bq + (size_t)l * T_ * H_, qbuf,
            N, H_, H_, (long)NH, (long)H_ * H_, (long)H_, (long)NH);
        // batched per-node per-relation softmax aggregation + GELU (in place)
        agg_all_kernel<<<dim3((N + 7) / 8, 3), dim3(512), 0, stream>>>(
            offs, esrc, qbuf, KV, p_rel + (size_t)l * R_ * HEADS_, scale2, N, E);
        // fused Wa-GEMM + skip + residual + LN + ReLU (writes h in place)
        gemm_ln_kernel<<<dim3(1, gM(N), 3), dim3(512), 0, stream>>>(
            qbuf, WaT + (size_t)l * T_ * H_ * H_, ba + (size_t)l * T_ * H_,
            h, skip + l * T_, ln_g + (size_t)l * T_ * H_, ln_b + (size_t)l * T_ * H_, N);
    }

    // shared output projection: h bf16 -> out fp32
    mfma_gemm<bf16_t, float, 0><<<dim3(OUT_ / 128, gM((long)T_ * N), 1), blk, 0, stream>>>(
        h, h, ZBIG, WoutT, bout, out, T_ * N, H_, OUT_, 0L, 0L, 0L, 0L);
}

// Round 19
// 392.969 us; speedup vs baseline: 1.0357x; 1.0357x over previous
//
#include <hip/hip_runtime.h>
#include <math.h>

// ---------------- constants from the reference ----------------
#define T_ 3
#define R_ 4
#define L_ 2
#define H_ 256
#define HEADS_ 8
#define D_ 32
#define FIN_ 128
#define OUT_ 128

typedef unsigned short bf16_t;
typedef __attribute__((ext_vector_type(8))) short bf16x8;
typedef __attribute__((ext_vector_type(4))) float f32x4;

__device__ __forceinline__ float bf2f(bf16_t h) {
    return __uint_as_float(((unsigned)h) << 16);
}
__device__ __forceinline__ float bflo(unsigned u) {
    return __uint_as_float(u << 16);
}
__device__ __forceinline__ float bfhi(unsigned u) {
    return __uint_as_float(u & 0xffff0000u);
}
__device__ __forceinline__ bf16_t f2bf(float f) {
    unsigned u = __float_as_uint(f);
    u += 0x7FFFu + ((u >> 16) & 1u);
    return (bf16_t)(u >> 16);
}
__device__ __forceinline__ float gelu_exact(float x) {
    return 0.5f * x * (1.0f + erff(x * 0.70710678118654752440f));
}
// packed bf16x2 dot: d = a.lo*b.lo + a.hi*b.hi + c   (VOP3P, CDNA2+)
__device__ __forceinline__ float dot2bf(unsigned a, unsigned b, float c) {
    float d;
    asm("v_dot2_f32_bf16 %0, %1, %2, %3" : "=v"(d) : "v"(a), "v"(b), "v"(c));
    return d;
}

// ---------------- zero fill ----------------
__global__ void zero_kernel(unsigned* __restrict__ p, long n) {
    long i = (long)blockIdx.x * blockDim.x + threadIdx.x;
    long stride = (long)gridDim.x * blockDim.x;
    for (; i < n; i += stride) p[i] = 0u;
}

// ---------------- all weight preprocessing in ONE kernel ----------------
// z 0..15: fused relation weights (+bias), K/V-interleaved (y=0..7, x=0..3)
// z 16..21: Wq transpose slices; 22..27: Wa; 28..30: Win; 31: Wout
__global__ __launch_bounds__(256) void prep_all_kernel(
    const float* __restrict__ Wk, const float* __restrict__ Wv,
    const float* __restrict__ bk, const float* __restrict__ bv,
    const float* __restrict__ a_rel, const float* __restrict__ m_rel,
    bf16_t* __restrict__ WkvT, float* __restrict__ bkv,
    const float* __restrict__ Wq, const float* __restrict__ Wa,
    const float* __restrict__ Win, const float* __restrict__ Wout,
    bf16_t* __restrict__ WqT, bf16_t* __restrict__ WaT,
    bf16_t* __restrict__ WinT, bf16_t* __restrict__ WoutT)
{
    const int tid = threadIdx.x;
    if (blockIdx.z < 16) {
        // ---- fuse path ----
        const int s = blockIdx.z;
        const int kv = s & 1, r = (s >> 1) & 3, l = s >> 3;
        const int SRCT[4] = {0, 1, 1, 1};
        const int st = SRCT[r];
        const float* W = (kv ? Wv : Wk) + ((long)l * T_ + st) * H_ * H_;
        const float* A = (kv ? m_rel : a_rel) + ((long)l * R_ + r) * HEADS_ * D_ * D_;
        const int hh = blockIdx.y, kt = blockIdx.x;
        __shared__ float As[32][33];
        __shared__ float Ws[64][33];
        {
            int d = tid >> 3, e4 = (tid & 7) * 4;
            float4 v = *(const float4*)(A + (hh * D_ + d) * D_ + e4);
            As[d][e4] = v.x; As[d][e4 + 1] = v.y; As[d][e4 + 2] = v.z; As[d][e4 + 3] = v.w;
        }
        #pragma unroll
        for (int p = 0; p < 2; ++p) {
            int idx = p * 256 + tid;
            int row = idx >> 3, c4 = (idx & 7) * 4;
            float4 v = *(const float4*)(W + (long)(kt * 64 + row) * H_ + hh * 32 + c4);
            Ws[row][c4] = v.x; Ws[row][c4 + 1] = v.y; Ws[row][c4 + 2] = v.z; Ws[row][c4 + 3] = v.w;
        }
        __syncthreads();
        const int kl = tid & 63, eb = tid >> 6;
        #pragma unroll
        for (int ii = 0; ii < 8; ++ii) {
            int e = eb * 8 + ii;
            float acc = 0.f;
            #pragma unroll
            for (int d = 0; d < 32; ++d)
                acc += As[d][e] * Ws[kl][d];
            int col = hh * 32 + e;
            int pos = (col >> 2) * 8 + kv * 4 + (col & 3);
            long rowIdx = (long)(s >> 1) * 512 + pos;
            WkvT[rowIdx * H_ + kt * 64 + kl] = f2bf(acc);
        }
        if (blockIdx.x == 0 && blockIdx.y == 0) {
            const float* b = (kv ? bv : bk) + ((long)l * T_ + st) * H_;
            const int bh = tid >> 5, be = tid & 31;
            float acc = 0.f;
            #pragma unroll
            for (int d = 0; d < D_; ++d)
                acc += b[bh * D_ + d] * A[(bh * D_ + d) * D_ + be];
            int pos = (tid >> 2) * 8 + kv * 4 + (tid & 3);
            bkv[(long)(s >> 1) * 512 + pos] = acc;
        }
    } else {
        // ---- transpose path ----
        __shared__ float Ls[64][65];
        int z = blockIdx.z - 16;
        const float* in; bf16_t* out; int Rr, Cc;
        if (z < 6)       { in = Wq;   out = WqT;   Rr = 256; Cc = 256; }
        else if (z < 12) { in = Wa;   out = WaT;   Rr = 256; Cc = 256; z -= 6; }
        else if (z < 15) { in = Win;  out = WinT;  Rr = 128; Cc = 256; z -= 12; }
        else             { in = Wout; out = WoutT; Rr = 256; Cc = 128; z = 0; }
        const int r0 = blockIdx.y * 64, c0 = blockIdx.x * 64;
        if (r0 >= Rr || c0 >= Cc || blockIdx.x >= 4) return;
        const long base = (long)z * Rr * Cc;
        #pragma unroll
        for (int i = 0; i < 16; ++i) {
            int e = tid + i * 256; int row = e >> 6, col = e & 63;
            Ls[row][col] = in[base + (long)(r0 + row) * Cc + c0 + col];
        }
        __syncthreads();
        #pragma unroll
        for (int i = 0; i < 16; ++i) {
            int e = tid + i * 256; int row = e >> 6, col = e & 63;
            out[base + (long)(c0 + row) * Rr + r0 + col] = f2bf(Ls[col][row]);
        }
    }
}

// ---------------- CSR build (parallel scan, 6 small launches) ----------------
__global__ void hist_kernel(const int* __restrict__ ei, int* __restrict__ indeg,
                            int Nn, int E)
{
    int idx = blockIdx.x * 256 + threadIdx.x;
    if (idx >= R_ * E) return;
    int r = idx / E, e = idx - r * E;
    int d = ei[(size_t)r * 2 * E + E + e];
    atomicAdd(indeg + (size_t)r * Nn + d, 1);
}

__global__ __launch_bounds__(256) void csr_part_kernel(
    const int* __restrict__ indeg, int* __restrict__ partials, int Nn, int nch)
{
    const int r = blockIdx.y, c = blockIdx.x, tid = threadIdx.x;
    const int lane = tid & 63, wave = tid >> 6;
    int idx = c * 256 + tid;
    int v = (idx < Nn) ? indeg[(size_t)r * Nn + idx] : 0;
    #pragma unroll
    for (int off = 1; off < 64; off <<= 1) v += __shfl_xor(v, off);
    __shared__ int wsum[4];
    if (lane == 0) wsum[wave] = v;
    __syncthreads();
    if (tid == 0) partials[r * nch + c] = wsum[0] + wsum[1] + wsum[2] + wsum[3];
}

__global__ __launch_bounds__(256) void csr_scanpart_kernel(
    int* __restrict__ partials, int nch)
{
    const int r = blockIdx.x, tid = threadIdx.x;
    __shared__ int sh[256];
    int v = (tid < nch) ? partials[r * nch + tid] : 0;
    sh[tid] = v;
    __syncthreads();
    for (int off = 1; off < 256; off <<= 1) {
        int u = (tid >= off) ? sh[tid - off] : 0;
        __syncthreads();
        sh[tid] += u;
        __syncthreads();
    }
    if (tid < nch) partials[r * nch + tid] = sh[tid] - v;   // exclusive
}

__global__ __launch_bounds__(256) void csr_write_kernel(
    const int* __restrict__ indeg, const int* __restrict__ partials,
    int* __restrict__ offs, int* __restrict__ cursor, int Nn, int nch)
{
    const int r = blockIdx.y, c = blockIdx.x, tid = threadIdx.x;
    int idx = c * 256 + tid;
    int v = (idx < Nn) ? indeg[(size_t)r * Nn + idx] : 0;
    __shared__ int sh[256];
    sh[tid] = v;
    __syncthreads();
    for (int off = 1; off < 256; off <<= 1) {
        int u = (tid >= off) ? sh[tid - off] : 0;
        __syncthreads();
        sh[tid] += u;
        __syncthreads();
    }
    int incl = sh[tid];
    int base = partials[r * nch + c];
    if (idx < Nn) {
        int excl = base + incl - v;
        offs[(size_t)r * (Nn + 1) + idx] = excl;
        cursor[(size_t)r * Nn + idx] = excl;
        if (idx == Nn - 1) offs[(size_t)r * (Nn + 1) + Nn] = base + incl;
    }
}

// esrc stores PRE-SCALED element offsets (src * 512)
__global__ void scatter_kernel(const int* __restrict__ ei, int* __restrict__ cursor,
                               int* __restrict__ esrc, int Nn, int E)
{
    int idx = blockIdx.x * 256 + threadIdx.x;
    if (idx >= R_ * E) return;
    int r = idx / E, e = idx - r * E;
    int s = ei[(size_t)r * 2 * E + e];
    int d = ei[(size_t)r * 2 * E + E + e];
    int pos = atomicAdd(cursor + (size_t)r * Nn + d, 1);
    esrc[(size_t)r * E + pos] = s * 512;
}

// ---------------- batched per-node attention aggregation ----------------
// 256-thread blocks (R17 measured optimum). Dual-chain batch-2, scalar state
// (rule #20), branchless validity, K/V interleaved rows, deferred-max exp2
// domain, v_dot2_f32_bf16 QK dot.
// Per-relation INDEPENDENT softmax; normalized results summed (matches ref).
#define STEP(rr, vld, prX, mX, sX, x0, x1, x2, x3)                          \
    {                                                                        \
        float dt_ = dot2bf(rr.y, quy, dot2bf(rr.x, qux, 0.f));               \
        dt_ += __shfl_xor(dt_, 1);                                           \
        dt_ += __shfl_xor(dt_, 2);                                           \
        dt_ += __shfl_xor(dt_, 4);                                           \
        float lg = (vld) ? dt_ * prX : -1e30f;                               \
        if (__any(lg - mX > 11.5415603f)) {                                  \
            float mn = fmaxf(mX, lg);                                        \
            float fac = exp2f(mX - mn);                                      \
            float p = exp2f(lg - mn);                                        \
            p = (vld) ? p : 0.f;                                             \
            sX = sX * fac + p;                                               \
            x0 = x0 * fac + p * bflo(rr.z);                                  \
            x1 = x1 * fac + p * bfhi(rr.z);                                  \
            x2 = x2 * fac + p * bflo(rr.w);                                  \
            x3 = x3 * fac + p * bfhi(rr.w);                                  \
            mX = mn;                                                         \
        } else {                                                             \
            float p = exp2f(lg - mX);                                        \
            p = (vld) ? p : 0.f;                                             \
            sX += p;                                                         \
            x0 += p * bflo(rr.z);                                            \
            x1 += p * bfhi(rr.z);                                            \
            x2 += p * bflo(rr.w);                                            \
            x3 += p * bfhi(rr.w);                                            \
        }                                                                    \
    }

__global__ __launch_bounds__(256) void agg_all_kernel(
    const int* __restrict__ offs, const int* __restrict__ esrc,
    bf16_t* __restrict__ qbuf, const bf16_t* __restrict__ KV,
    const float* __restrict__ p_l, float scale2, int Nn, int E)
{
    static const int NRELg[3] = {2, 1, 1};
    static const int R0g[3]  = {0, 1, 3};
    static const int R1g[3]  = {2, 0, 0};
    static const int DTg[3]  = {1, 0, 2};
    const int grp = blockIdx.y;
    const int wave = threadIdx.x >> 6, lane = threadIdx.x & 63;
    const int d = blockIdx.x * 4 + wave;
    if (d >= Nn) return;
    const int head = lane >> 3;
    const int dt = DTg[grp];
    const bool separate = (NRELg[grp] == 2);

    bf16_t* qrow = qbuf + ((size_t)dt * Nn + d) * H_;
    uint2 qu = ((const uint2*)qrow)[lane];
    const unsigned qux = qu.x, quy = qu.y;

    const int rA = R0g[grp];
    const int* esA = esrc + (size_t)rA * E;
    const bf16_t* kvA = KV + (size_t)rA * Nn * 512;
    float prA = p_l[rA * HEADS_ + head] * scale2;
    int curA = offs[(size_t)rA * (Nn + 1) + d];
    int endA = offs[(size_t)rA * (Nn + 1) + d + 1];

    const int* esB; const bf16_t* kvB; float prB;
    int curB, endB;
    if (separate) {
        const int rB = R1g[grp];
        esB = esrc + (size_t)rB * E;
        kvB = KV + (size_t)rB * Nn * 512;
        prB = p_l[rB * HEADS_ + head] * scale2;
        curB = offs[(size_t)rB * (Nn + 1) + d];
        endB = offs[(size_t)rB * (Nn + 1) + d + 1];
    } else {
        int mid = curA + ((endA - curA + 1) >> 1);
        esB = esA; kvB = kvA; prB = prA;
        curB = mid; endB = endA;
        endA = mid;
    }
    const int safeA = (endA > 0) ? endA - 1 : 0;
    const int safeB = (endB > 0) ? endB - 1 : 0;
    const int loff = lane * 8;

    float mA = -INFINITY, sA = 0.f, aA0 = 0.f, aA1 = 0.f, aA2 = 0.f, aA3 = 0.f;
    float mB = -INFINITY, sB = 0.f, aB0 = 0.f, aB1 = 0.f, aB2 = 0.f, aB3 = 0.f;

    while (curA < endA || curB < endB) {
        bool vA0 = curA < endA, vA1 = curA + 1 < endA;
        bool vB0 = curB < endB, vB1 = curB + 1 < endB;
        uint4 rA0, rA1, rB0, rB1;
        if (vA0) {
            int i0 = esA[curA];
            int i1 = esA[min(curA + 1, safeA)];
            rA0 = *(const uint4*)(kvA + i0 + loff);
            rA1 = *(const uint4*)(kvA + i1 + loff);
        }
        if (vB0) {
            int i0 = esB[curB];
            int i1 = esB[min(curB + 1, safeB)];
            rB0 = *(const uint4*)(kvB + i0 + loff);
            rB1 = *(const uint4*)(kvB + i1 + loff);
        }
        if (vA0) {
            STEP(rA0, true, prA, mA, sA, aA0, aA1, aA2, aA3)
            STEP(rA1, vA1, prA, mA, sA, aA0, aA1, aA2, aA3)
            curA += 2;
        }
        if (vB0) {
            STEP(rB0, true, prB, mB, sB, aB0, aB1, aB2, aB3)
            STEP(rB1, vB1, prB, mB, sB, aB0, aB1, aB2, aB3)
            curB += 2;
        }
    }

    float t0, t1, t2, t3;
    if (separate) {
        float iA = (sA > 0.f) ? 1.f / sA : 0.f;
        float iB = (sB > 0.f) ? 1.f / sB : 0.f;
        t0 = aA0 * iA + aB0 * iB;
        t1 = aA1 * iA + aB1 * iB;
        t2 = aA2 * iA + aB2 * iB;
        t3 = aA3 * iA + aB3 * iB;
    } else {
        if (sB > 0.f) {   // exact merge of the two half-range chains
            float mm = fmaxf(mA, mB);
            float fx = (sA > 0.f) ? exp2f(mA - mm) : 0.f;
            float fy = exp2f(mB - mm);
            sA = sA * fx + sB * fy;
            aA0 = aA0 * fx + aB0 * fy;
            aA1 = aA1 * fx + aB1 * fy;
            aA2 = aA2 * fx + aB2 * fy;
            aA3 = aA3 * fx + aB3 * fy;
        }
        float iA = (sA > 0.f) ? 1.f / sA : 0.f;
        t0 = aA0 * iA; t1 = aA1 * iA; t2 = aA2 * iA; t3 = aA3 * iA;
    }
    ushort4 ou;
    ou.x = f2bf(gelu_exact(t0));
    ou.y = f2bf(gelu_exact(t1));
    ou.z = f2bf(gelu_exact(t2));
    ou.w = f2bf(gelu_exact(t3));
    ((ushort4*)qrow)[lane] = ou;
}

// ---------------- MFMA bf16 GEMM ----------------
// Epilogue staging buffer ALIASES As (dead after the K loop).
#define ASTR 40
#define ESTR 72

template<typename TA, typename TC, int ACT_C>
__global__ __launch_bounds__(256) void mfma_gemm(
    const TA* __restrict__ A, const TA* __restrict__ A2, int zsplit,
    const bf16_t* __restrict__ BT,
    const float* __restrict__ bias, TC* __restrict__ C,
    int M, int K, int Nc,
    long strideA, long strideB, long strideBias, long strideC)
{
    const int gX = gridDim.x, gY = gridDim.y, gZ = gridDim.z;
    const int nwg = gX * gY * gZ;
    int flat = blockIdx.x + gX * (blockIdx.y + gY * blockIdx.z);
    const int qch = nwg >> 3, rch = nwg & 7;
    int xcd = flat & 7, cidx = flat >> 3;
    int swz = (xcd < rch ? xcd * (qch + 1) : rch * (qch + 1) + (xcd - rch) * qch) + cidx;
    const int by = swz / (gX * gZ);
    int rem = swz - by * (gX * gZ);
    const int bz = rem / gX;
    const int bx = rem - bz * gX;

    const TA* Ab = (bz < zsplit) ? (A + (long)bz * strideA) : A2;
    const bf16_t* Bb = BT + (long)bz * strideB;
    const float* biasb = bias + (long)bz * strideBias;
    TC* Cb = C + (long)bz * strideC;

    __shared__ bf16_t As[128 * ASTR];
    __shared__ bf16_t Bs[128 * ASTR];
    const int tid = threadIdx.x;
    const int lane = tid & 63, wave = tid >> 6;
    const int wr = wave >> 1, wc = wave & 1;
    const int bm = by * 128, bn = bx * 128;
    const int r16 = lane & 15, g = lane >> 4;
    f32x4 acc[4][4] = {};

    for (int k0 = 0; k0 < K; k0 += 32) {
        #pragma unroll
        for (int p = 0; p < 2; ++p) {
            int idx = p * 256 + tid;
            int row = idx >> 2, seg = idx & 3;
            int grow = bm + row;
            bf16x8 av = {};
            if (grow < M) {
                if constexpr (sizeof(TA) == 2) {
                    av = *(const bf16x8*)(Ab + (long)grow * K + k0 + seg * 8);
                } else {
                    const float* sp = (const float*)Ab + (long)grow * K + k0 + seg * 8;
                    float4 f0 = *(const float4*)sp, f1 = *(const float4*)(sp + 4);
                    av[0] = (short)f2bf(f0.x); av[1] = (short)f2bf(f0.y);
                    av[2] = (short)f2bf(f0.z); av[3] = (short)f2bf(f0.w);
                    av[4] = (short)f2bf(f1.x); av[5] = (short)f2bf(f1.y);
                    av[6] = (short)f2bf(f1.z); av[7] = (short)f2bf(f1.w);
                }
            }
            *(bf16x8*)(As + row * ASTR + seg * 8) = av;
            bf16x8 bv = *(const bf16x8*)(Bb + (long)(bn + row) * K + k0 + seg * 8);
            *(bf16x8*)(Bs + row * ASTR + seg * 8) = bv;
        }
        __syncthreads();
        bf16x8 af[4], bfr[4];
        #pragma unroll
        for (int m = 0; m < 4; ++m)
            af[m] = *(const bf16x8*)(As + (wr * 64 + m * 16 + r16) * ASTR + g * 8);
        #pragma unroll
        for (int n = 0; n < 4; ++n)
            bfr[n] = *(const bf16x8*)(Bs + (wc * 64 + n * 16 + r16) * ASTR + g * 8);
        #pragma unroll
        for (int m = 0; m < 4; ++m)
            #pragma unroll
            for (int n = 0; n < 4; ++n)
                acc[m][n] = __builtin_amdgcn_mfma_f32_16x16x32_bf16(af[m], bfr[n], acc[m][n], 0, 0, 0);
        __syncthreads();
    }

    float bb[4];
    #pragma unroll
    for (int n = 0; n < 4; ++n)
        bb[n] = biasb[bn + wc * 64 + n * 16 + r16];

    if constexpr (sizeof(TC) == 2) {
        bf16_t* st = As + wave * (16 * ESTR);   // Es aliases As (dead)
        #pragma unroll
        for (int m = 0; m < 4; ++m) {
            int rowbase = bm + wr * 64 + m * 16;
            #pragma unroll
            for (int n = 0; n < 4; ++n) {
                #pragma unroll
                for (int j = 0; j < 4; ++j) {
                    float vv = acc[m][n][j] + bb[n];
                    if (ACT_C) vv = fmaxf(vv, 0.f);
                    st[(g * 4 + j) * ESTR + n * 16 + r16] = f2bf(vv);
                }
            }
            #pragma unroll
            for (int p = 0; p < 2; ++p) {
                int row = p * 8 + (lane >> 3);
                int col0 = (lane & 7) * 8;
                int grow = rowbase + row;
                bf16x8 val = *(const bf16x8*)(st + row * ESTR + col0);
                if (grow < M)
                    *(bf16x8*)(Cb + (long)grow * Nc + bn + wc * 64 + col0) = val;
            }
        }
    } else {
        #pragma unroll
        for (int n = 0; n < 4; ++n) {
            int col = bn + wc * 64 + n * 16 + r16;
            #pragma unroll
            for (int m = 0; m < 4; ++m) {
                int rowbase = bm + wr * 64 + m * 16 + g * 4;
                #pragma unroll
                for (int j = 0; j < 4; ++j) {
                    int row = rowbase + j;
                    if (row < M) {
                        float vv = acc[m][n][j] + bb[n];
                        if (ACT_C) vv = fmaxf(vv, 0.f);
                        Cb[(long)row * Nc + col] = vv;
                    }
                }
            }
        }
    }
}

// ---------------- fused Wa-GEMM + skip-gate + residual + LN + ReLU ----------
// Epilogue/residual staging ALIASES Bs (dead after K loop).
__global__ __launch_bounds__(512) void gemm_ln_kernel(
    const bf16_t* __restrict__ A, const bf16_t* __restrict__ BT,
    const float* __restrict__ bias, bf16_t* __restrict__ h,
    const float* __restrict__ skip_l, const float* __restrict__ ln_g,
    const float* __restrict__ ln_b, int M)
{
    const int gY = gridDim.y;
    const int nwg = gY * 3;
    int flat = blockIdx.y + gY * blockIdx.z;
    const int qch = nwg >> 3, rch = nwg & 7;
    int xcd = flat & 7, cidx = flat >> 3;
    int swz = (xcd < rch ? xcd * (qch + 1) : rch * (qch + 1) + (xcd - rch) * qch) + cidx;
    const int by = swz / 3;
    const int bz = swz - by * 3;

    const bf16_t* Ab = A + (long)bz * M * H_;
    const bf16_t* Bb = BT + (long)bz * H_ * H_;
    const float* biasb = bias + bz * H_;
    bf16_t* hb = h + (long)bz * M * H_;
    const float* lgp = ln_g + bz * H_;
    const float* lbp = ln_b + bz * H_;

    __shared__ bf16_t As[128 * ASTR];
    __shared__ bf16_t Bs[256 * ASTR];
    __shared__ float  sums[128][4][2];

    const int tid = threadIdx.x;
    const int lane = tid & 63, wave = tid >> 6;
    const int wr = wave >> 2, wc = wave & 3;
    const int bm = by * 128;
    const int r16 = lane & 15, g = lane >> 4;
    f32x4 acc[4][4] = {};

    for (int k0 = 0; k0 < H_; k0 += 32) {
        {
            int row = tid >> 2, seg = tid & 3;
            int grow = bm + row;
            bf16x8 av = {};
            if (grow < M) av = *(const bf16x8*)(Ab + (long)grow * H_ + k0 + seg * 8);
            *(bf16x8*)(As + row * ASTR + seg * 8) = av;
        }
        #pragma unroll
        for (int p = 0; p < 2; ++p) {
            int idx = p * 512 + tid;
            int row = idx >> 2, seg = idx & 3;
            bf16x8 bv = *(const bf16x8*)(Bb + (long)row * H_ + k0 + seg * 8);
            *(bf16x8*)(Bs + row * ASTR + seg * 8) = bv;
        }
        __syncthreads();
        bf16x8 af[4], bfr[4];
        #pragma unroll
        for (int m = 0; m < 4; ++m)
            af[m] = *(const bf16x8*)(As + (wr * 64 + m * 16 + r16) * ASTR + g * 8);
        #pragma unroll
        for (int n = 0; n < 4; ++n)
            bfr[n] = *(const bf16x8*)(Bs + (wc * 64 + n * 16 + r16) * ASTR + g * 8);
        #pragma unroll
        for (int m = 0; m < 4; ++m)
            #pragma unroll
            for (int n = 0; n < 4; ++n)
                acc[m][n] = __builtin_amdgcn_mfma_f32_16x16x32_bf16(af[m], bfr[n], acc[m][n], 0, 0, 0);
        __syncthreads();
    }

    const float beta = 1.f / (1.f + __expf(-skip_l[bz]));
    const float cb = 2.f - beta;
    const int colb = wc * 64;
    float bb[4], lng[4], lnb[4];
    #pragma unroll
    for (int n = 0; n < 4; ++n) {
        int col = colb + n * 16 + r16;
        bb[n] = biasb[col]; lng[n] = lgp[col]; lnb[n] = lbp[col];
    }

    bf16_t* st = Bs + wave * (16 * ESTR);
    #pragma unroll
    for (int m = 0; m < 4; ++m) {
        #pragma unroll
        for (int p = 0; p < 2; ++p) {
            int row = p * 8 + (lane >> 3);
            int col0 = (lane & 7) * 8;
            int grow = bm + wr * 64 + m * 16 + row;
            bf16x8 hv = {};
            if (grow < M) hv = *(const bf16x8*)(hb + (long)grow * H_ + colb + col0);
            *(bf16x8*)(st + row * ESTR + col0) = hv;
        }
        #pragma unroll
        for (int j = 0; j < 4; ++j) {
            int lrow = wr * 64 + m * 16 + g * 4 + j;
            float s1 = 0.f, s2 = 0.f;
            #pragma unroll
            for (int n = 0; n < 4; ++n) {
                float o = acc[m][n][j] + bb[n];
                float hv = bf2f(st[(g * 4 + j) * ESTR + n * 16 + r16]);
                float u = beta * o + cb * hv;
                acc[m][n][j] = u;
                s1 += u; s2 += u * u;
            }
            s1 += __shfl_xor(s1, 1); s2 += __shfl_xor(s2, 1);
            s1 += __shfl_xor(s1, 2); s2 += __shfl_xor(s2, 2);
            s1 += __shfl_xor(s1, 4); s2 += __shfl_xor(s2, 4);
            s1 += __shfl_xor(s1, 8); s2 += __shfl_xor(s2, 8);
            if (r16 == 0) { sums[lrow][wc][0] = s1; sums[lrow][wc][1] = s2; }
        }
    }
    __syncthreads();

    #pragma unroll
    for (int m = 0; m < 4; ++m) {
        #pragma unroll
        for (int j = 0; j < 4; ++j) {
            int lrow = wr * 64 + m * 16 + g * 4 + j;
            float S1 = sums[lrow][0][0] + sums[lrow][1][0] + sums[lrow][2][0] + sums[lrow][3][0];
            float S2 = sums[lrow][0][1] + sums[lrow][1][1] + sums[lrow][2][1] + sums[lrow][3][1];
            float mu = S1 * (1.f / H_);
            float var = S2 * (1.f / H_) - mu * mu;
            float inv = rsqrtf(var + 1e-5f);
            #pragma unroll
            for (int n = 0; n < 4; ++n) {
                float r = fmaxf((acc[m][n][j] - mu) * inv * lng[n] + lnb[n], 0.f);
                st[(g * 4 + j) * ESTR + n * 16 + r16] = f2bf(r);
            }
        }
        #pragma unroll
        for (int p = 0; p < 2; ++p) {
            int row = p * 8 + (lane >> 3);
            int col0 = (lane & 7) * 8;
            int grow = bm + wr * 64 + m * 16 + row;
            bf16x8 val = *(const bf16x8*)(st + row * ESTR + col0);
            if (grow < M)
                *(bf16x8*)(hb + (long)grow * H_ + colb + col0) = val;
        }
    }
}

// ---------------- host side ----------------
extern "C" void kernel_launch(void* const* d_in, const int* in_sizes, int n_in,
                              void* d_out, int out_size, void* d_ws, size_t ws_size,
                              hipStream_t stream)
{
    const float* x     = (const float*)d_in[0];
    const int*   ei    = (const int*)  d_in[1];
    const float* Win   = (const float*)d_in[2];
    const float* b_in  = (const float*)d_in[3];
    const float* Wk    = (const float*)d_in[4];
    const float* bk    = (const float*)d_in[5];
    const float* Wq    = (const float*)d_in[6];
    const float* bq    = (const float*)d_in[7];
    const float* Wv    = (const float*)d_in[8];
    const float* bv    = (const float*)d_in[9];
    const float* Wa    = (const float*)d_in[10];
    const float* ba    = (const float*)d_in[11];
    const float* skip  = (const float*)d_in[12];
    const float* a_rel = (const float*)d_in[13];
    const float* m_rel = (const float*)d_in[14];
    const float* p_rel = (const float*)d_in[15];
    const float* ln_g  = (const float*)d_in[16];
    const float* ln_b  = (const float*)d_in[17];
    const float* Wout  = (const float*)d_in[18];
    const float* bout  = (const float*)d_in[19];
    float* out = (float*)d_out;

    const int N = in_sizes[0] / (T_ * FIN_);
    const int E = in_sizes[1] / (R_ * 2);
    const size_t NH = (size_t)N * H_;
    const int nch = (N + 255) / 256;
    const int ZBIG = 1 << 20;

    char* wp = (char*)d_ws;
    auto alloc = [&](size_t bytes) {
        void* r = wp;
        wp += (bytes + 255) & ~(size_t)255;
        return r;
    };
    bf16_t* h     = (bf16_t*)alloc(T_ * NH * 2);
    bf16_t* qbuf  = (bf16_t*)alloc(T_ * NH * 2);
    bf16_t* KV    = (bf16_t*)alloc((size_t)R_ * N * 512 * 2);
    int*    indeg = (int*)   alloc((size_t)R_ * N * 4);
    int*    offs  = (int*)   alloc((size_t)R_ * (N + 1) * 4);
    int*    cursor= (int*)   alloc((size_t)R_ * N * 4);
    int*    esrc  = (int*)   alloc((size_t)R_ * E * 4);
    int*    parts = (int*)   alloc((size_t)R_ * 256 * 4);
    bf16_t* WqT   = (bf16_t*)alloc((size_t)L_ * T_ * H_ * H_ * 2);
    bf16_t* WaT   = (bf16_t*)alloc((size_t)L_ * T_ * H_ * H_ * 2);
    bf16_t* WinT  = (bf16_t*)alloc((size_t)T_ * FIN_ * H_ * 2);
    bf16_t* WoutT = (bf16_t*)alloc((size_t)H_ * OUT_ * 2);
    bf16_t* WkvT  = (bf16_t*)alloc((size_t)L_ * R_ * 512 * H_ * 2);
    float*  bkv   = (float*) alloc((size_t)L_ * R_ * 512 * 4);

    if ((size_t)(wp - (char*)d_ws) > ws_size) return;   // clean-fail guard

    const float scale2 = 0.17677669529663688f * 1.4426950408889634f;  // /sqrt(32)*log2e
    dim3 blk(256);
    auto gM = [](long M) { return (int)((M + 127) / 128); };

    // ---- weight preprocessing (1 launch) ----
    prep_all_kernel<<<dim3(4, 8, 32), blk, 0, stream>>>(
        Wk, Wv, bk, bv, a_rel, m_rel, WkvT, bkv,
        Wq, Wa, Win, Wout, WqT, WaT, WinT, WoutT);

    // ---- CSR build (parallel, 6 small launches) ----
    zero_kernel<<<256, blk, 0, stream>>>((unsigned*)indeg, (long)R_ * N);
    hist_kernel<<<(R_ * E + 255) / 256, blk, 0, stream>>>(ei, indeg, N, E);
    csr_part_kernel<<<dim3(nch, R_), blk, 0, stream>>>(indeg, parts, N, nch);
    csr_scanpart_kernel<<<R_, blk, 0, stream>>>(parts, nch);
    csr_write_kernel<<<dim3(nch, R_), blk, 0, stream>>>(indeg, parts, offs, cursor, N, nch);
    scatter_kernel<<<(R_ * E + 255) / 256, blk, 0, stream>>>(ei, cursor, esrc, N, E);

    // ---- input projection + relu ----
    mfma_gemm<float, bf16_t, 1><<<dim3(H_ / 128, gM(N), T_), blk, 0, stream>>>(
        x, x, ZBIG, WinT, b_in, h, N, FIN_, H_,
        (long)N * FIN_, (long)FIN_ * H_, H_, (long)NH);

    for (int l = 0; l < L_; ++l) {
        const long lw = (long)l * R_;
        // KV for all 4 relations (interleaved k|v columns): z=4
        mfma_gemm<bf16_t, bf16_t, 0><<<dim3(512 / 128, gM(N), 4), blk, 0, stream>>>(
            h, h + NH, 1, WkvT + lw * 512 * H_, bkv + lw * 512, KV,
            N, H_, 512, 0L, 512L * H_, 512L, (long)N * 512);
        // q for all 3 node types: z=3
        mfma_gemm<bf16_t, bf16_t, 0><<<dim3(H_ / 128, gM(N), 3), blk, 0, stream>>>(
            h, h, ZBIG, WqT + (size_t)l * T_ * H_ * H_, bq + (size_t)l * T_ * H_, qbuf,
            N, H_, H_, (long)NH, (long)H_ * H_, (long)H_, (long)NH);
        // batched per-node per-relation softmax aggregation + GELU (in place)
        agg_all_kernel<<<dim3((N + 3) / 4, 3), blk, 0, stream>>>(
            offs, esrc, qbuf, KV, p_rel + (size_t)l * R_ * HEADS_, scale2, N, E);
        // fused Wa-GEMM + skip + residual + LN + ReLU (writes h in place)
        gemm_ln_kernel<<<dim3(1, gM(N), 3), dim3(512), 0, stream>>>(
            qbuf, WaT + (size_t)l * T_ * H_ * H_, ba + (size_t)l * T_ * H_,
            h, skip + l * T_, ln_g + (size_t)l * T_ * H_, ln_b + (size_t)l * T_ * H_, N);
    }

    // shared output projection: h bf16 -> out fp32
    mfma_gemm<bf16_t, float, 0><<<dim3(OUT_ / 128, gM((long)T_ * N), 1), blk, 0, stream>>>(
        h, h, ZBIG, WoutT, bout, out, T_ * N, H_, OUT_, 0L, 0L, 0L, 0L);
}